// Round 8
// baseline (331.665 us; speedup 1.0000x reference)
//
#include <hip/hip_runtime.h>
#include <hip/hip_fp16.h>

// 2-layer GCN, CSR-gather formulation (no float atomics).
// A_norm·(x@W1) = (A_norm·x)@W1 -> layer-1 aggregation in 12-ch space.
// CSR payload = int2{row, norm}. k_fill: 4-way dest-partitioned writes
// (per-XCD L2 write window) + non-temporal edge-stream reads (no L2 pollution).
// h2 and x gathered as fp16 (halves gather traffic; error << threshold).

#define IN_CH 12
#define HID 128
#define OUTC 64
#define PADK 132  // A-tile row stride in floats for gemm2 (breaks pow2 bank stride)

__global__ void k_zero_i(int* __restrict__ p, int n) {
    int i = blockIdx.x * blockDim.x + threadIdx.x;
    if (i < n) p[i] = 0;
}

// x16 = fp16(x)
__global__ void k_cvt(const float* __restrict__ x, __half* __restrict__ x16, int n) {
    int i = blockIdx.x * blockDim.x + threadIdx.x;
    if (i < n) x16[i] = __float2half(x[i]);
}

__global__ void k_count(const int* __restrict__ col, int* __restrict__ cnt, int E) {
    int e = blockIdx.x * blockDim.x + threadIdx.x;
    if (e < E) {
        int c = __builtin_nontemporal_load(col + e);
        atomicAdd(&cnt[c], 1);
    }
}

// dinv[i]=rsqrt(cnt[i]+1); start[i]=exclusive running offset (cur stays zeroed)
__global__ __launch_bounds__(256) void k_alloc(
    const int* __restrict__ cnt, float* __restrict__ dinv,
    int* __restrict__ start, int* __restrict__ total, int N) {
    __shared__ int sdata[256];
    __shared__ int sbase;
    int i = blockIdx.x * 256 + threadIdx.x;
    int v = (i < N) ? cnt[i] : 0;
    if (i < N) dinv[i] = rsqrtf((float)v + 1.0f);
    sdata[threadIdx.x] = v;
    __syncthreads();
#pragma unroll
    for (int off = 1; off < 256; off <<= 1) {
        int t = (threadIdx.x >= off) ? sdata[threadIdx.x - off] : 0;
        __syncthreads();
        sdata[threadIdx.x] += t;
        __syncthreads();
    }
    if (threadIdx.x == 255) sbase = atomicAdd(total, sdata[255]);
    __syncthreads();
    if (i < N) start[i] = sbase + sdata[threadIdx.x] - v;  // exclusive scan
}

// 4-way destination-partitioned fill. Block b handles dest range (b&3):
// per-XCD dirty write window = 3.2MB (fits 4MB L2); nt loads keep the
// redundant row/col streams from evicting it.
__global__ void k_fill(const int* __restrict__ row, const int* __restrict__ col,
                       const float* __restrict__ dinv, const int* __restrict__ start,
                       int* __restrict__ cur, int2* __restrict__ edges,
                       int E, int per) {
    int part  = blockIdx.x & 3;
    int chunk = blockIdx.x >> 2;
    int e = chunk * 256 + threadIdx.x;
    if (e >= E) return;
    int c = __builtin_nontemporal_load(col + e);
    int lo = part * per;
    if (c < lo || c >= lo + per) return;
    int r = __builtin_nontemporal_load(row + e);
    int p = start[c] + atomicAdd(&cur[c], 1);
    edges[p] = make_int2(r, __float_as_int(dinv[r] * dinv[c]));
}

// aggx[n] = sum_{e->n} x[row_e]*norm_e + x[n]*dinv^2   (12 channels, x in fp16)
// block = 192 threads = 16 nodes x 12 lanes
__global__ __launch_bounds__(192) void k_gather_x(
    const int* __restrict__ start, const int* __restrict__ cnt,
    const float* __restrict__ dinv, const int2* __restrict__ edges,
    const __half* __restrict__ x16, float* __restrict__ aggx, int N) {
    int ln = threadIdx.x / 12;
    int c  = threadIdx.x % 12;
    int n  = blockIdx.x * 16 + ln;
    if (n >= N) return;
    float dv = dinv[n];
    float acc = __half2float(x16[(size_t)n * IN_CH + c]) * dv * dv;
    int s0 = start[n], k = cnt[n];
    int j = 0;
    for (; j + 4 <= k; j += 4) {
        int2 e0 = edges[s0 + j + 0], e1 = edges[s0 + j + 1];
        int2 e2 = edges[s0 + j + 2], e3 = edges[s0 + j + 3];
        float v0 = __half2float(x16[(size_t)e0.x * IN_CH + c]);
        float v1 = __half2float(x16[(size_t)e1.x * IN_CH + c]);
        float v2 = __half2float(x16[(size_t)e2.x * IN_CH + c]);
        float v3 = __half2float(x16[(size_t)e3.x * IN_CH + c]);
        acc = fmaf(v0, __int_as_float(e0.y), acc);
        acc = fmaf(v1, __int_as_float(e1.y), acc);
        acc = fmaf(v2, __int_as_float(e2.y), acc);
        acc = fmaf(v3, __int_as_float(e3.y), acc);
    }
    for (; j < k; ++j) {
        int2 e = edges[s0 + j];
        acc = fmaf(__half2float(x16[(size_t)e.x * IN_CH + c]), __int_as_float(e.y), acc);
    }
    aggx[(size_t)n * IN_CH + c] = acc;
}

// out1 = relu(aggx @ W1 + b1)   (block = 256 threads, 16 nodes x 128 ch)
__global__ __launch_bounds__(256) void k_gemm1b(
    const float* __restrict__ aggx, const float* __restrict__ W1,
    const float* __restrict__ b1, float* __restrict__ out1, int N) {
    __shared__ float w1s[IN_CH * HID];  // 6 KiB
    __shared__ float axs[16][IN_CH];    // 768 B
    for (int i = threadIdx.x; i < IN_CH * HID; i += 256) w1s[i] = W1[i];
    long long base = (long long)blockIdx.x * 16;
    if (threadIdx.x < 16 * IN_CH) {
        int r = threadIdx.x / IN_CH, k = threadIdx.x % IN_CH;
        long long n = base + r;
        axs[r][k] = (n < N) ? aggx[n * IN_CH + k] : 0.0f;
    }
    __syncthreads();
    int c    = threadIdx.x & 127;
    int half = threadIdx.x >> 7;
    float bb = b1[c];
    float acc[8];
#pragma unroll
    for (int j = 0; j < 8; ++j) acc[j] = bb;
#pragma unroll
    for (int k = 0; k < IN_CH; ++k) {
        float w = w1s[k * HID + c];
#pragma unroll
        for (int j = 0; j < 8; ++j)
            acc[j] = fmaf(axs[half * 8 + j][k], w, acc[j]);
    }
#pragma unroll
    for (int j = 0; j < 8; ++j) {
        long long n = base + half * 8 + j;
        if (n < N) out1[n * HID + c] = fmaxf(acc[j], 0.0f);
    }
}

// h2 = out1 @ W2 (fp16 output): LDS-tiled GEMM, 64x64 tile, 4x4 reg tile/thread
__global__ __launch_bounds__(256) void k_gemm2(
    const float* __restrict__ out1, const float* __restrict__ W2,
    __half* __restrict__ h2, int N) {
    __shared__ float as[64 * PADK];   // 33.8 KiB
    __shared__ float ws[HID * OUTC];  // 32 KiB
    for (int i = threadIdx.x; i < (HID * OUTC) / 4; i += 256)
        ((float4*)ws)[i] = ((const float4*)W2)[i];
    long long base = (long long)blockIdx.x * 64;
    for (int i = threadIdx.x; i < 2048; i += 256) {
        int r = i >> 5, kq = i & 31;
        long long rr = base + r; if (rr >= N) rr = N - 1;
        float4 v = ((const float4*)(out1 + rr * HID))[kq];
        *(float4*)(as + r * PADK + 4 * kq) = v;
    }
    __syncthreads();
    int tc = threadIdx.x & 15;
    int tr = threadIdx.x >> 4;
    float acc[4][4] = {};
    const float* ar = as + 4 * tr * PADK;
#pragma unroll 8
    for (int k = 0; k < HID; k += 4) {
        float4 a[4], w[4];
#pragma unroll
        for (int j = 0; j < 4; ++j) a[j] = *(const float4*)(ar + j * PADK + k);
#pragma unroll
        for (int kk = 0; kk < 4; ++kk) w[kk] = *(const float4*)(ws + (k + kk) * OUTC + 4 * tc);
#pragma unroll
        for (int kk = 0; kk < 4; ++kk) {
            float aw[4] = {w[kk].x, w[kk].y, w[kk].z, w[kk].w};
#pragma unroll
            for (int j = 0; j < 4; ++j) {
                float av = (kk == 0) ? a[j].x : (kk == 1) ? a[j].y : (kk == 2) ? a[j].z : a[j].w;
                acc[j][0] = fmaf(av, aw[0], acc[j][0]);
                acc[j][1] = fmaf(av, aw[1], acc[j][1]);
                acc[j][2] = fmaf(av, aw[2], acc[j][2]);
                acc[j][3] = fmaf(av, aw[3], acc[j][3]);
            }
        }
    }
#pragma unroll
    for (int j = 0; j < 4; ++j) {
        long long r = base + 4 * tr + j;
        if (r < N) {
            __half2* d = (__half2*)(h2 + r * OUTC + 4 * tc);
            d[0] = __floats2half2_rn(acc[j][0], acc[j][1]);
            d[1] = __floats2half2_rn(acc[j][2], acc[j][3]);
        }
    }
}

// out = sum h2[row_e]*norm_e + h2[n]*dinv^2 + b2   (wave = 1 node, lane = channel)
__global__ __launch_bounds__(256) void k_gather2(
    const int* __restrict__ start, const int* __restrict__ cnt,
    const float* __restrict__ dinv, const int2* __restrict__ edges,
    const __half* __restrict__ h2, const float* __restrict__ b2,
    float* __restrict__ out, int N) {
    int ln = threadIdx.x >> 6;
    int c  = threadIdx.x & 63;
    int n  = blockIdx.x * 4 + ln;
    if (n >= N) return;
    float dv = dinv[n];
    float acc = fmaf(__half2float(h2[(size_t)n * OUTC + c]), dv * dv, b2[c]);
    int s0 = start[n], k = cnt[n];
    int j = 0;
    for (; j + 4 <= k; j += 4) {
        int2 e0 = edges[s0 + j + 0], e1 = edges[s0 + j + 1];
        int2 e2 = edges[s0 + j + 2], e3 = edges[s0 + j + 3];
        float v0 = __half2float(h2[(size_t)e0.x * OUTC + c]);
        float v1 = __half2float(h2[(size_t)e1.x * OUTC + c]);
        float v2 = __half2float(h2[(size_t)e2.x * OUTC + c]);
        float v3 = __half2float(h2[(size_t)e3.x * OUTC + c]);
        acc = fmaf(v0, __int_as_float(e0.y), acc);
        acc = fmaf(v1, __int_as_float(e1.y), acc);
        acc = fmaf(v2, __int_as_float(e2.y), acc);
        acc = fmaf(v3, __int_as_float(e3.y), acc);
    }
    for (; j < k; ++j) {
        int2 e = edges[s0 + j];
        acc = fmaf(__half2float(h2[(size_t)e.x * OUTC + c]), __int_as_float(e.y), acc);
    }
    out[(size_t)n * OUTC + c] = acc;
}

extern "C" void kernel_launch(void* const* d_in, const int* in_sizes, int n_in,
                              void* d_out, int out_size, void* d_ws, size_t ws_size,
                              hipStream_t stream) {
    const float* x  = (const float*)d_in[0];
    const int*   ei = (const int*)d_in[1];
    const float* W1 = (const float*)d_in[2];
    const float* b1 = (const float*)d_in[3];
    const float* W2 = (const float*)d_in[4];
    const float* b2 = (const float*)d_in[5];
    float* out = (float*)d_out;

    const int N = in_sizes[0] / IN_CH;
    const int E = in_sizes[1] / 2;
    const int* row = ei;
    const int* col = ei + E;

    char* ws = (char*)d_ws;
    int*   cnt   = (int*)ws;                       // N
    int*   cur   = cnt + N;                        // N
    int*   total = cur + N;                        // 1 (cnt..total: 2N+1 ints zeroed)
    int*   start = total + 64;                     // N
    float* dinv  = (float*)(start + N + 64);       // N
    char*  p     = (char*)(dinv + N);
    p = (char*)(((uintptr_t)p + 255) & ~(uintptr_t)255);
    int2*  edges = (int2*)p;                       // E int2 (12.8 MB)
    float* aggx  = (float*)(edges + E);            // N*12
    float* out1  = aggx + (size_t)N * IN_CH;       // N*128
    __half* h2   = (__half*)(out1 + (size_t)N * HID);   // N*64 fp16 (12.8 MB)
    __half* x16  = h2 + (size_t)N * OUTC;          // N*12 fp16 (2.4 MB)

    const int per    = (N + 3) / 4;                // destination range size
    const int chunks = (E + 255) / 256;

    k_zero_i<<<(2 * N + 1 + 255) / 256, 256, 0, stream>>>(cnt, 2 * N + 1);
    k_cvt<<<(N * IN_CH + 255) / 256, 256, 0, stream>>>(x, x16, N * IN_CH);
    k_count<<<chunks, 256, 0, stream>>>(col, cnt, E);
    k_alloc<<<(N + 255) / 256, 256, 0, stream>>>(cnt, dinv, start, total, N);
    k_fill<<<chunks * 4, 256, 0, stream>>>(row, col, dinv, start, cur, edges, E, per);

    k_gather_x<<<(N + 15) / 16, 192, 0, stream>>>(start, cnt, dinv, edges, x16, aggx, N);
    k_gemm1b<<<(N + 15) / 16, 256, 0, stream>>>(aggx, W1, b1, out1, N);
    k_gemm2<<<(N + 63) / 64, 256, 0, stream>>>(out1, W2, h2, N);
    k_gather2<<<(N + 3) / 4, 256, 0, stream>>>(start, cnt, dinv, edges, h2, b2, out, N);
}

// Round 9
// 218.994 us; speedup vs baseline: 1.5145x; 1.5145x over previous
//
#include <hip/hip_runtime.h>
#include <hip/hip_fp16.h>

// 2-layer GCN, CSR-gather formulation (no float atomics).
// A_norm·(x@W1) = (A_norm·x)@W1 -> layer-1 aggregation in 12-ch space.
// CSR built by two-level LDS bucket sort (dense run-coalesced writes; scattered
// single-pass fill was measured sector-bound at 64B/edge in r4/r7/r8).
// CSR payload = row index only; norm = dinv[r]*dinv[n] computed in gathers.
// x and h2 gathered as fp16 (error << threshold, measured r8).

#define IN_CH 12
#define HID 128
#define OUTC 64
#define PADK 132   // A-tile row stride in floats for gemm2 (breaks pow2 bank stride)
#define BSH 7      // bucket = 128 dest nodes
#define NBMAX 1024 // supports N <= 131072
#define CHUNK 8192 // edges per k_bucket block

__global__ void k_zero_i(int* __restrict__ p, int n) {
    int i = blockIdx.x * blockDim.x + threadIdx.x;
    if (i < n) p[i] = 0;
}

__global__ void k_cvt(const float* __restrict__ x, __half* __restrict__ x16, int n) {
    int i = blockIdx.x * blockDim.x + threadIdx.x;
    if (i < n) x16[i] = __float2half(x[i]);
}

// ---- CSR build pass 1: bucket histogram (LDS-privatized) ----
__global__ __launch_bounds__(256) void k_bhist(
    const int* __restrict__ col, int* __restrict__ bcnt, int E, int NB) {
    __shared__ int lh[NBMAX];
    int t = threadIdx.x;
    for (int i = t; i < NB; i += 256) lh[i] = 0;
    __syncthreads();
    int base = blockIdx.x * CHUNK;
    int end = min(base + CHUNK, E);
    for (int e = base + t; e < end; e += 256)
        atomicAdd(&lh[col[e] >> BSH], 1);
    __syncthreads();
    for (int i = t; i < NB; i += 256)
        if (lh[i]) atomicAdd(&bcnt[i], lh[i]);
}

// ---- pass 2: scan bucket counts -> bstart, gcur; also start[N]=E ----
__global__ __launch_bounds__(256) void k_bscan(
    const int* __restrict__ bcnt, int* __restrict__ bstart,
    int* __restrict__ gcur, int* __restrict__ startN, int E, int NB) {
    __shared__ int part[256];
    int t = threadIdx.x;
    int v[4]; int s = 0;
#pragma unroll
    for (int j = 0; j < 4; ++j) { int b = t * 4 + j; v[j] = (b < NB) ? bcnt[b] : 0; s += v[j]; }
    part[t] = s;
    __syncthreads();
    for (int off = 1; off < 256; off <<= 1) {
        int u = (t >= off) ? part[t - off] : 0;
        __syncthreads();
        part[t] += u;
        __syncthreads();
    }
    int base = (t > 0) ? part[t - 1] : 0;
#pragma unroll
    for (int j = 0; j < 4; ++j) {
        int b = t * 4 + j;
        if (b < NB) { bstart[b] = base; gcur[b] = base; }
        base += v[j];
    }
    if (t == 255) bstart[NB] = base;  // == E
    if (t == 0) *startN = E;          // start[N] = E
}

// ---- pass 3: LDS-staged bucket append (run-coalesced global writes) ----
__global__ __launch_bounds__(256) void k_bucket(
    const int* __restrict__ row, const int* __restrict__ col,
    int* __restrict__ gcur, int2* __restrict__ bbuf, int E, int NB) {
    __shared__ int lh[NBMAX], lstart[NBMAX], lcur[NBMAX], gb[NBMAX];
    __shared__ int part[256];
    __shared__ int2 lbuf[CHUNK];  // 64 KiB
    int t = threadIdx.x;
    for (int i = t; i < NB; i += 256) lh[i] = 0;
    __syncthreads();
    int base0 = blockIdx.x * CHUNK;
    int end = min(base0 + CHUNK, E);
    for (int e = base0 + t; e < end; e += 256)
        atomicAdd(&lh[col[e] >> BSH], 1);
    __syncthreads();
    // exclusive scan of lh (4 entries/thread)
    int v[4]; int s = 0;
#pragma unroll
    for (int j = 0; j < 4; ++j) { int b = t * 4 + j; v[j] = (b < NB) ? lh[b] : 0; s += v[j]; }
    part[t] = s;
    __syncthreads();
    for (int off = 1; off < 256; off <<= 1) {
        int u = (t >= off) ? part[t - off] : 0;
        __syncthreads();
        part[t] += u;
        __syncthreads();
    }
    int pb = (t > 0) ? part[t - 1] : 0;
#pragma unroll
    for (int j = 0; j < 4; ++j) {
        int b = t * 4 + j;
        if (b < NB) lstart[b] = pb;
        pb += v[j];
    }
    __syncthreads();
    // bulk reservation: one global atomic per (block, bucket)
    for (int i = t; i < NB; i += 256) {
        int c = lh[i];
        gb[i] = c ? atomicAdd(&gcur[i], c) : 0;
        lcur[i] = lstart[i];
    }
    __syncthreads();
    // place edges into LDS grouped by bucket
    for (int e = base0 + t; e < end; e += 256) {
        int c = col[e];
        int p = atomicAdd(&lcur[c >> BSH], 1);
        lbuf[p] = make_int2(row[e], c);
    }
    __syncthreads();
    // copy-out: consecutive i within a bucket run -> consecutive global addrs
    int cN = end - base0;
    for (int i = t; i < cN; i += 256) {
        int2 rc = lbuf[i];
        int b = rc.y >> BSH;
        bbuf[gb[b] + (i - lstart[b])] = rc;
    }
}

// ---- pass 4: per-bucket local CSR: start/dinv/rs (all writes in small window) ----
__global__ __launch_bounds__(256) void k_csr(
    const int* __restrict__ bstart, const int2* __restrict__ bbuf,
    int* __restrict__ start, float* __restrict__ dinv,
    int* __restrict__ rs, int N) {
    int me = blockIdx.x;
    int lo = me << BSH;
    int bs = bstart[me], be = bstart[me + 1];
    int cntb = be - bs;
    __shared__ int lh[128], lsc[128];
    int t = threadIdx.x;
    if (t < 128) lh[t] = 0;
    __syncthreads();
    for (int i = t; i < cntb; i += 256)
        atomicAdd(&lh[bbuf[bs + i].y - lo], 1);
    __syncthreads();
    if (t < 128) lsc[t] = lh[t];
    __syncthreads();
    for (int off = 1; off < 128; off <<= 1) {
        int u = (t < 128 && t >= off) ? lsc[t - off] : 0;
        __syncthreads();
        if (t < 128) lsc[t] += u;
        __syncthreads();
    }
    if (t < 128) {
        int excl = lsc[t] - lh[t];
        int n = lo + t;
        if (n < N) {
            start[n] = bs + excl;
            dinv[n] = rsqrtf((float)lh[t] + 1.0f);
        }
        lsc[t] = excl;  // reuse as cursor
    }
    __syncthreads();
    for (int i = t; i < cntb; i += 256) {
        int2 rc = bbuf[bs + i];
        int p = atomicAdd(&lsc[rc.y - lo], 1);
        rs[bs + p] = rc.x;
    }
}

// ---- layer 1 gather: aggx = A_norm·x (12 ch, fp16 x, norm on the fly) ----
__global__ __launch_bounds__(192) void k_gather_x(
    const int* __restrict__ start, const float* __restrict__ dinv,
    const int* __restrict__ rs, const __half* __restrict__ x16,
    float* __restrict__ aggx, int N) {
    int ln = threadIdx.x / 12;
    int c  = threadIdx.x % 12;
    int n  = blockIdx.x * 16 + ln;
    if (n >= N) return;
    float dv = dinv[n];
    int s0 = start[n], k = start[n + 1] - s0;
    float acc = __half2float(x16[(size_t)n * IN_CH + c]) * dv * dv;
    int j = 0;
    for (; j + 4 <= k; j += 4) {
        int r0 = rs[s0 + j], r1 = rs[s0 + j + 1], r2 = rs[s0 + j + 2], r3 = rs[s0 + j + 3];
        float n0 = dinv[r0] * dv, n1 = dinv[r1] * dv, n2 = dinv[r2] * dv, n3 = dinv[r3] * dv;
        float v0 = __half2float(x16[(size_t)r0 * IN_CH + c]);
        float v1 = __half2float(x16[(size_t)r1 * IN_CH + c]);
        float v2 = __half2float(x16[(size_t)r2 * IN_CH + c]);
        float v3 = __half2float(x16[(size_t)r3 * IN_CH + c]);
        acc = fmaf(v0, n0, acc);
        acc = fmaf(v1, n1, acc);
        acc = fmaf(v2, n2, acc);
        acc = fmaf(v3, n3, acc);
    }
    for (; j < k; ++j) {
        int r = rs[s0 + j];
        acc = fmaf(__half2float(x16[(size_t)r * IN_CH + c]), dinv[r] * dv, acc);
    }
    aggx[(size_t)n * IN_CH + c] = acc;
}

// out1 = relu(aggx @ W1 + b1)   (block = 256 threads, 16 nodes x 128 ch)
__global__ __launch_bounds__(256) void k_gemm1b(
    const float* __restrict__ aggx, const float* __restrict__ W1,
    const float* __restrict__ b1, float* __restrict__ out1, int N) {
    __shared__ float w1s[IN_CH * HID];
    __shared__ float axs[16][IN_CH];
    for (int i = threadIdx.x; i < IN_CH * HID; i += 256) w1s[i] = W1[i];
    long long base = (long long)blockIdx.x * 16;
    if (threadIdx.x < 16 * IN_CH) {
        int r = threadIdx.x / IN_CH, k = threadIdx.x % IN_CH;
        long long n = base + r;
        axs[r][k] = (n < N) ? aggx[n * IN_CH + k] : 0.0f;
    }
    __syncthreads();
    int c    = threadIdx.x & 127;
    int half = threadIdx.x >> 7;
    float bb = b1[c];
    float acc[8];
#pragma unroll
    for (int j = 0; j < 8; ++j) acc[j] = bb;
#pragma unroll
    for (int k = 0; k < IN_CH; ++k) {
        float w = w1s[k * HID + c];
#pragma unroll
        for (int j = 0; j < 8; ++j)
            acc[j] = fmaf(axs[half * 8 + j][k], w, acc[j]);
    }
#pragma unroll
    for (int j = 0; j < 8; ++j) {
        long long n = base + half * 8 + j;
        if (n < N) out1[n * HID + c] = fmaxf(acc[j], 0.0f);
    }
}

// h2 = out1 @ W2 (fp16 output): LDS-tiled GEMM, 64x64 tile, 4x4 reg tile/thread
__global__ __launch_bounds__(256) void k_gemm2(
    const float* __restrict__ out1, const float* __restrict__ W2,
    __half* __restrict__ h2, int N) {
    __shared__ float as[64 * PADK];
    __shared__ float ws[HID * OUTC];
    for (int i = threadIdx.x; i < (HID * OUTC) / 4; i += 256)
        ((float4*)ws)[i] = ((const float4*)W2)[i];
    long long base = (long long)blockIdx.x * 64;
    for (int i = threadIdx.x; i < 2048; i += 256) {
        int r = i >> 5, kq = i & 31;
        long long rr = base + r; if (rr >= N) rr = N - 1;
        float4 v = ((const float4*)(out1 + rr * HID))[kq];
        *(float4*)(as + r * PADK + 4 * kq) = v;
    }
    __syncthreads();
    int tc = threadIdx.x & 15;
    int tr = threadIdx.x >> 4;
    float acc[4][4] = {};
    const float* ar = as + 4 * tr * PADK;
#pragma unroll 8
    for (int k = 0; k < HID; k += 4) {
        float4 a[4], w[4];
#pragma unroll
        for (int j = 0; j < 4; ++j) a[j] = *(const float4*)(ar + j * PADK + k);
#pragma unroll
        for (int kk = 0; kk < 4; ++kk) w[kk] = *(const float4*)(ws + (k + kk) * OUTC + 4 * tc);
#pragma unroll
        for (int kk = 0; kk < 4; ++kk) {
            float aw[4] = {w[kk].x, w[kk].y, w[kk].z, w[kk].w};
#pragma unroll
            for (int j = 0; j < 4; ++j) {
                float av = (kk == 0) ? a[j].x : (kk == 1) ? a[j].y : (kk == 2) ? a[j].z : a[j].w;
                acc[j][0] = fmaf(av, aw[0], acc[j][0]);
                acc[j][1] = fmaf(av, aw[1], acc[j][1]);
                acc[j][2] = fmaf(av, aw[2], acc[j][2]);
                acc[j][3] = fmaf(av, aw[3], acc[j][3]);
            }
        }
    }
#pragma unroll
    for (int j = 0; j < 4; ++j) {
        long long r = base + 4 * tr + j;
        if (r < N) {
            __half2* d = (__half2*)(h2 + r * OUTC + 4 * tc);
            d[0] = __floats2half2_rn(acc[j][0], acc[j][1]);
            d[1] = __floats2half2_rn(acc[j][2], acc[j][3]);
        }
    }
}

// out = sum h2[r]*dinv[r]*dv + h2[n]*dv^2 + b2   (wave = 1 node, lane = channel)
__global__ __launch_bounds__(256) void k_gather2(
    const int* __restrict__ start, const float* __restrict__ dinv,
    const int* __restrict__ rs, const __half* __restrict__ h2,
    const float* __restrict__ b2, float* __restrict__ out, int N) {
    int ln = threadIdx.x >> 6;
    int c  = threadIdx.x & 63;
    int n  = blockIdx.x * 4 + ln;
    if (n >= N) return;
    float dv = dinv[n];
    int s0 = start[n], k = start[n + 1] - s0;
    float acc = fmaf(__half2float(h2[(size_t)n * OUTC + c]), dv * dv, b2[c]);
    int j = 0;
    for (; j + 4 <= k; j += 4) {
        int r0 = rs[s0 + j], r1 = rs[s0 + j + 1], r2 = rs[s0 + j + 2], r3 = rs[s0 + j + 3];
        float n0 = dinv[r0] * dv, n1 = dinv[r1] * dv, n2 = dinv[r2] * dv, n3 = dinv[r3] * dv;
        float v0 = __half2float(h2[(size_t)r0 * OUTC + c]);
        float v1 = __half2float(h2[(size_t)r1 * OUTC + c]);
        float v2 = __half2float(h2[(size_t)r2 * OUTC + c]);
        float v3 = __half2float(h2[(size_t)r3 * OUTC + c]);
        acc = fmaf(v0, n0, acc);
        acc = fmaf(v1, n1, acc);
        acc = fmaf(v2, n2, acc);
        acc = fmaf(v3, n3, acc);
    }
    for (; j < k; ++j) {
        int r = rs[s0 + j];
        acc = fmaf(__half2float(h2[(size_t)r * OUTC + c]), dinv[r] * dv, acc);
    }
    out[(size_t)n * OUTC + c] = acc;
}

extern "C" void kernel_launch(void* const* d_in, const int* in_sizes, int n_in,
                              void* d_out, int out_size, void* d_ws, size_t ws_size,
                              hipStream_t stream) {
    const float* x  = (const float*)d_in[0];
    const int*   ei = (const int*)d_in[1];
    const float* W1 = (const float*)d_in[2];
    const float* b1 = (const float*)d_in[3];
    const float* W2 = (const float*)d_in[4];
    const float* b2 = (const float*)d_in[5];
    float* out = (float*)d_out;

    const int N = in_sizes[0] / IN_CH;
    const int E = in_sizes[1] / 2;
    const int* row = ei;
    const int* col = ei + E;
    const int NB = (N + 127) >> BSH;  // 782 for N=100000 (<= NBMAX)

    char* ws = (char*)d_ws;
    int*    bcnt   = (int*)ws;                      // NB (zeroed)
    int*    bstart = bcnt + NBMAX;                  // NB+1
    int*    gcur   = bstart + NBMAX + 8;            // NB
    int*    start  = gcur + NBMAX;                  // N+1
    float*  dinv   = (float*)(start + N + 8);       // N
    char*   p      = (char*)(dinv + N);
    p = (char*)(((uintptr_t)p + 255) & ~(uintptr_t)255);
    int2*   bbuf   = (int2*)p;                      // E int2 (12.8 MB)
    int*    rs     = (int*)(bbuf + E);              // E int (6.4 MB)
    __half* x16    = (__half*)(rs + E);             // N*12 fp16
    float*  aggx   = (float*)(x16 + (size_t)N * IN_CH + 8);   // N*12 f32
    float*  out1   = aggx + (size_t)N * IN_CH;      // N*128 f32
    __half* h2     = (__half*)(out1 + (size_t)N * HID);       // N*64 fp16

    const int nchunks = (E + CHUNK - 1) / CHUNK;

    k_zero_i<<<(NB + 255) / 256, 256, 0, stream>>>(bcnt, NB);
    k_cvt<<<(N * IN_CH + 255) / 256, 256, 0, stream>>>(x, x16, N * IN_CH);
    k_bhist<<<nchunks, 256, 0, stream>>>(col, bcnt, E, NB);
    k_bscan<<<1, 256, 0, stream>>>(bcnt, bstart, gcur, start + N, E, NB);
    k_bucket<<<nchunks, 256, 0, stream>>>(row, col, gcur, bbuf, E, NB);
    k_csr<<<NB, 256, 0, stream>>>(bstart, bbuf, start, dinv, rs, N);

    k_gather_x<<<(N + 15) / 16, 192, 0, stream>>>(start, dinv, rs, x16, aggx, N);
    k_gemm1b<<<(N + 15) / 16, 256, 0, stream>>>(aggx, W1, b1, out1, N);
    k_gemm2<<<(N + 63) / 64, 256, 0, stream>>>(out1, W2, h2, N);
    k_gather2<<<(N + 3) / 4, 256, 0, stream>>>(start, dinv, rs, h2, b2, out, N);
}

// Round 10
// 194.505 us; speedup vs baseline: 1.7052x; 1.1259x over previous
//
#include <hip/hip_runtime.h>
#include <hip/hip_fp16.h>

// 2-layer GCN, CSR-gather formulation (no float atomics).
// A_norm·(x@W1) = (A_norm·x)@W1 -> layer-1 aggregation in 12-ch space.
// CSR built by two-level LDS bucket sort (run-coalesced writes; scattered
// single-pass fill measured sector-bound at 64B/edge in r4/r7/r8).
// CSR payload = row index only; norm = dinv[r]*dinv[n] computed in gathers.
// x and h2 gathered as fp16 (error << threshold, measured r8/r9).
// MLP (W1+relu+W2) fused per 64-node tile: out1 never hits global.

#define IN_CH 12
#define HID 128
#define OUTC 64
#define PADK 132   // hidden-tile row stride in floats (breaks pow2 bank stride)
#define BSH 7      // bucket = 128 dest nodes
#define NBMAX 1024 // supports N <= 131072
#define CHUNK 4096 // edges per k_bucket block (32KB lbuf -> 3 blocks/CU)

__global__ void k_zero_i(int* __restrict__ p, int n) {
    int i = blockIdx.x * blockDim.x + threadIdx.x;
    if (i < n) p[i] = 0;
}

__global__ void k_cvt(const float* __restrict__ x, __half* __restrict__ x16, int n) {
    int i = blockIdx.x * blockDim.x + threadIdx.x;
    if (i < n) x16[i] = __float2half(x[i]);
}

// ---- CSR build pass 1: bucket histogram (LDS-privatized) ----
__global__ __launch_bounds__(256) void k_bhist(
    const int* __restrict__ col, int* __restrict__ bcnt, int E, int NB) {
    __shared__ int lh[NBMAX];
    int t = threadIdx.x;
    for (int i = t; i < NB; i += 256) lh[i] = 0;
    __syncthreads();
    int base = blockIdx.x * CHUNK;
    int end = min(base + CHUNK, E);
    for (int e = base + t; e < end; e += 256)
        atomicAdd(&lh[col[e] >> BSH], 1);
    __syncthreads();
    for (int i = t; i < NB; i += 256)
        if (lh[i]) atomicAdd(&bcnt[i], lh[i]);
}

// ---- pass 2: scan bucket counts -> bstart, gcur; also start[N]=E ----
__global__ __launch_bounds__(256) void k_bscan(
    const int* __restrict__ bcnt, int* __restrict__ bstart,
    int* __restrict__ gcur, int* __restrict__ startN, int E, int NB) {
    __shared__ int part[256];
    int t = threadIdx.x;
    int v[4]; int s = 0;
#pragma unroll
    for (int j = 0; j < 4; ++j) { int b = t * 4 + j; v[j] = (b < NB) ? bcnt[b] : 0; s += v[j]; }
    part[t] = s;
    __syncthreads();
    for (int off = 1; off < 256; off <<= 1) {
        int u = (t >= off) ? part[t - off] : 0;
        __syncthreads();
        part[t] += u;
        __syncthreads();
    }
    int base = (t > 0) ? part[t - 1] : 0;
#pragma unroll
    for (int j = 0; j < 4; ++j) {
        int b = t * 4 + j;
        if (b < NB) { bstart[b] = base; gcur[b] = base; }
        base += v[j];
    }
    if (t == 255) bstart[NB] = base;  // == E
    if (t == 0) *startN = E;          // start[N] = E
}

// ---- pass 3: LDS-staged bucket append (run-coalesced global writes) ----
__global__ __launch_bounds__(256) void k_bucket(
    const int* __restrict__ row, const int* __restrict__ col,
    int* __restrict__ gcur, int2* __restrict__ bbuf, int E, int NB) {
    __shared__ int lh[NBMAX], lstart[NBMAX], lcur[NBMAX], gb[NBMAX];
    __shared__ int part[256];
    __shared__ int2 lbuf[CHUNK];  // 32 KiB
    int t = threadIdx.x;
    for (int i = t; i < NB; i += 256) lh[i] = 0;
    __syncthreads();
    int base0 = blockIdx.x * CHUNK;
    int end = min(base0 + CHUNK, E);
    for (int e = base0 + t; e < end; e += 256)
        atomicAdd(&lh[col[e] >> BSH], 1);
    __syncthreads();
    int v[4]; int s = 0;
#pragma unroll
    for (int j = 0; j < 4; ++j) { int b = t * 4 + j; v[j] = (b < NB) ? lh[b] : 0; s += v[j]; }
    part[t] = s;
    __syncthreads();
    for (int off = 1; off < 256; off <<= 1) {
        int u = (t >= off) ? part[t - off] : 0;
        __syncthreads();
        part[t] += u;
        __syncthreads();
    }
    int pb = (t > 0) ? part[t - 1] : 0;
#pragma unroll
    for (int j = 0; j < 4; ++j) {
        int b = t * 4 + j;
        if (b < NB) lstart[b] = pb;
        pb += v[j];
    }
    __syncthreads();
    for (int i = t; i < NB; i += 256) {
        int c = lh[i];
        gb[i] = c ? atomicAdd(&gcur[i], c) : 0;
        lcur[i] = lstart[i];
    }
    __syncthreads();
    for (int e = base0 + t; e < end; e += 256) {
        int c = col[e];
        int p = atomicAdd(&lcur[c >> BSH], 1);
        lbuf[p] = make_int2(row[e], c);
    }
    __syncthreads();
    int cN = end - base0;
    for (int i = t; i < cN; i += 256) {
        int2 rc = lbuf[i];
        int b = rc.y >> BSH;
        bbuf[gb[b] + (i - lstart[b])] = rc;
    }
}

// ---- pass 4: per-bucket local CSR: start/dinv/rs (all writes in small window) ----
__global__ __launch_bounds__(256) void k_csr(
    const int* __restrict__ bstart, const int2* __restrict__ bbuf,
    int* __restrict__ start, float* __restrict__ dinv,
    int* __restrict__ rs, int N) {
    int me = blockIdx.x;
    int lo = me << BSH;
    int bs = bstart[me], be = bstart[me + 1];
    int cntb = be - bs;
    __shared__ int lh[128], lsc[128];
    int t = threadIdx.x;
    if (t < 128) lh[t] = 0;
    __syncthreads();
    for (int i = t; i < cntb; i += 256)
        atomicAdd(&lh[bbuf[bs + i].y - lo], 1);
    __syncthreads();
    if (t < 128) lsc[t] = lh[t];
    __syncthreads();
    for (int off = 1; off < 128; off <<= 1) {
        int u = (t < 128 && t >= off) ? lsc[t - off] : 0;
        __syncthreads();
        if (t < 128) lsc[t] += u;
        __syncthreads();
    }
    if (t < 128) {
        int excl = lsc[t] - lh[t];
        int n = lo + t;
        if (n < N) {
            start[n] = bs + excl;
            dinv[n] = rsqrtf((float)lh[t] + 1.0f);
        }
        lsc[t] = excl;  // reuse as cursor
    }
    __syncthreads();
    for (int i = t; i < cntb; i += 256) {
        int2 rc = bbuf[bs + i];
        int p = atomicAdd(&lsc[rc.y - lo], 1);
        rs[bs + p] = rc.x;
    }
}

// ---- layer 1 gather: aggx = A_norm·x (12 ch, fp16 x, 8-deep pipeline) ----
__global__ __launch_bounds__(192) void k_gather_x(
    const int* __restrict__ start, const float* __restrict__ dinv,
    const int* __restrict__ rs, const __half* __restrict__ x16,
    float* __restrict__ aggx, int N) {
    int ln = threadIdx.x / 12;
    int c  = threadIdx.x % 12;
    int n  = blockIdx.x * 16 + ln;
    if (n >= N) return;
    float dv = dinv[n];
    int s0 = start[n], k = start[n + 1] - s0;
    float acc = __half2float(x16[(size_t)n * IN_CH + c]) * dv * dv;
    int j = 0;
    for (; j + 8 <= k; j += 8) {
        int r[8];
#pragma unroll
        for (int q = 0; q < 8; ++q) r[q] = rs[s0 + j + q];
        float nm[8], vv[8];
#pragma unroll
        for (int q = 0; q < 8; ++q) nm[q] = dinv[r[q]] * dv;
#pragma unroll
        for (int q = 0; q < 8; ++q) vv[q] = __half2float(x16[(size_t)r[q] * IN_CH + c]);
#pragma unroll
        for (int q = 0; q < 8; ++q) acc = fmaf(vv[q], nm[q], acc);
    }
    for (; j + 4 <= k; j += 4) {
        int r0 = rs[s0 + j], r1 = rs[s0 + j + 1], r2 = rs[s0 + j + 2], r3 = rs[s0 + j + 3];
        float n0 = dinv[r0] * dv, n1 = dinv[r1] * dv, n2 = dinv[r2] * dv, n3 = dinv[r3] * dv;
        float v0 = __half2float(x16[(size_t)r0 * IN_CH + c]);
        float v1 = __half2float(x16[(size_t)r1 * IN_CH + c]);
        float v2 = __half2float(x16[(size_t)r2 * IN_CH + c]);
        float v3 = __half2float(x16[(size_t)r3 * IN_CH + c]);
        acc = fmaf(v0, n0, acc); acc = fmaf(v1, n1, acc);
        acc = fmaf(v2, n2, acc); acc = fmaf(v3, n3, acc);
    }
    for (; j < k; ++j) {
        int r = rs[s0 + j];
        acc = fmaf(__half2float(x16[(size_t)r * IN_CH + c]), dinv[r] * dv, acc);
    }
    aggx[(size_t)n * IN_CH + c] = acc;
}

// ---- fused MLP: h2 = fp16( relu(aggx@W1 + b1) @ W2 ), per 64-node tile ----
__global__ __launch_bounds__(256) void k_mlp(
    const float* __restrict__ aggx, const float* __restrict__ W1,
    const float* __restrict__ b1, const float* __restrict__ W2,
    __half* __restrict__ h2, int N) {
    __shared__ float w1s[IN_CH * HID];   // 6 KiB
    __shared__ float ws[HID * OUTC];     // 32 KiB
    __shared__ float axs[64 * IN_CH];    // 3 KiB
    __shared__ float hs[64 * PADK];      // 33.8 KiB
    int t = threadIdx.x;
    for (int i = t; i < (HID * OUTC) / 4; i += 256)
        ((float4*)ws)[i] = ((const float4*)W2)[i];
    for (int i = t; i < IN_CH * HID; i += 256) w1s[i] = W1[i];
    long long base = (long long)blockIdx.x * 64;
    for (int i = t; i < 64 * IN_CH; i += 256) {
        long long n = base + i / IN_CH;
        axs[i] = (n < N) ? aggx[base * IN_CH + i] : 0.0f;
    }
    __syncthreads();
    // hidden: hs[row][k] = relu(sum_j axs[row][j]*W1[j][k] + b1[k])
    {
        int k    = t & 127;
        int half = t >> 7;
        float w[IN_CH];
#pragma unroll
        for (int j = 0; j < IN_CH; ++j) w[j] = w1s[j * HID + k];
        float bb = b1[k];
        for (int r = 0; r < 32; ++r) {
            int row = half * 32 + r;
            float acc = bb;
#pragma unroll
            for (int j = 0; j < IN_CH; ++j)
                acc = fmaf(axs[row * IN_CH + j], w[j], acc);
            hs[row * PADK + k] = fmaxf(acc, 0.0f);
        }
    }
    __syncthreads();
    // output: 64x64 tile, 4x4 register tile per thread
    int tc = t & 15;
    int tr = t >> 4;
    float acc[4][4] = {};
    const float* ar = hs + 4 * tr * PADK;
#pragma unroll 8
    for (int k = 0; k < HID; k += 4) {
        float4 a[4], w[4];
#pragma unroll
        for (int j = 0; j < 4; ++j) a[j] = *(const float4*)(ar + j * PADK + k);
#pragma unroll
        for (int kk = 0; kk < 4; ++kk) w[kk] = *(const float4*)(ws + (k + kk) * OUTC + 4 * tc);
#pragma unroll
        for (int kk = 0; kk < 4; ++kk) {
            float aw[4] = {w[kk].x, w[kk].y, w[kk].z, w[kk].w};
#pragma unroll
            for (int j = 0; j < 4; ++j) {
                float av = (kk == 0) ? a[j].x : (kk == 1) ? a[j].y : (kk == 2) ? a[j].z : a[j].w;
                acc[j][0] = fmaf(av, aw[0], acc[j][0]);
                acc[j][1] = fmaf(av, aw[1], acc[j][1]);
                acc[j][2] = fmaf(av, aw[2], acc[j][2]);
                acc[j][3] = fmaf(av, aw[3], acc[j][3]);
            }
        }
    }
#pragma unroll
    for (int j = 0; j < 4; ++j) {
        long long r = base + 4 * tr + j;
        if (r < N) {
            __half2* d = (__half2*)(h2 + r * OUTC + 4 * tc);
            d[0] = __floats2half2_rn(acc[j][0], acc[j][1]);
            d[1] = __floats2half2_rn(acc[j][2], acc[j][3]);
        }
    }
}

// ---- layer 2 gather: out = A_norm·h2 + b2 (64 ch, fp16 h2, 8-deep pipeline) ----
__global__ __launch_bounds__(256) void k_gather2(
    const int* __restrict__ start, const float* __restrict__ dinv,
    const int* __restrict__ rs, const __half* __restrict__ h2,
    const float* __restrict__ b2, float* __restrict__ out, int N) {
    int ln = threadIdx.x >> 6;
    int c  = threadIdx.x & 63;
    int n  = blockIdx.x * 4 + ln;
    if (n >= N) return;
    float dv = dinv[n];
    int s0 = start[n], k = start[n + 1] - s0;
    float acc = fmaf(__half2float(h2[(size_t)n * OUTC + c]), dv * dv, b2[c]);
    int j = 0;
    for (; j + 8 <= k; j += 8) {
        int r[8];
#pragma unroll
        for (int q = 0; q < 8; ++q) r[q] = rs[s0 + j + q];
        float nm[8], vv[8];
#pragma unroll
        for (int q = 0; q < 8; ++q) nm[q] = dinv[r[q]] * dv;
#pragma unroll
        for (int q = 0; q < 8; ++q) vv[q] = __half2float(h2[(size_t)r[q] * OUTC + c]);
#pragma unroll
        for (int q = 0; q < 8; ++q) acc = fmaf(vv[q], nm[q], acc);
    }
    for (; j + 4 <= k; j += 4) {
        int r0 = rs[s0 + j], r1 = rs[s0 + j + 1], r2 = rs[s0 + j + 2], r3 = rs[s0 + j + 3];
        float n0 = dinv[r0] * dv, n1 = dinv[r1] * dv, n2 = dinv[r2] * dv, n3 = dinv[r3] * dv;
        float v0 = __half2float(h2[(size_t)r0 * OUTC + c]);
        float v1 = __half2float(h2[(size_t)r1 * OUTC + c]);
        float v2 = __half2float(h2[(size_t)r2 * OUTC + c]);
        float v3 = __half2float(h2[(size_t)r3 * OUTC + c]);
        acc = fmaf(v0, n0, acc); acc = fmaf(v1, n1, acc);
        acc = fmaf(v2, n2, acc); acc = fmaf(v3, n3, acc);
    }
    for (; j < k; ++j) {
        int r = rs[s0 + j];
        acc = fmaf(__half2float(h2[(size_t)r * OUTC + c]), dinv[r] * dv, acc);
    }
    out[(size_t)n * OUTC + c] = acc;
}

extern "C" void kernel_launch(void* const* d_in, const int* in_sizes, int n_in,
                              void* d_out, int out_size, void* d_ws, size_t ws_size,
                              hipStream_t stream) {
    const float* x  = (const float*)d_in[0];
    const int*   ei = (const int*)d_in[1];
    const float* W1 = (const float*)d_in[2];
    const float* b1 = (const float*)d_in[3];
    const float* W2 = (const float*)d_in[4];
    const float* b2 = (const float*)d_in[5];
    float* out = (float*)d_out;

    const int N = in_sizes[0] / IN_CH;
    const int E = in_sizes[1] / 2;
    const int* row = ei;
    const int* col = ei + E;
    const int NB = (N + 127) >> BSH;  // 782 for N=100000 (<= NBMAX)

    char* ws = (char*)d_ws;
    int*    bcnt   = (int*)ws;                      // NB (zeroed)
    int*    bstart = bcnt + NBMAX;                  // NB+1
    int*    gcur   = bstart + NBMAX + 8;            // NB
    int*    start  = gcur + NBMAX;                  // N+1
    float*  dinv   = (float*)(start + N + 8);       // N
    char*   p      = (char*)(dinv + N);
    p = (char*)(((uintptr_t)p + 255) & ~(uintptr_t)255);
    int2*   bbuf   = (int2*)p;                      // E int2 (12.8 MB)
    int*    rs     = (int*)(bbuf + E);              // E int (6.4 MB)
    __half* x16    = (__half*)(rs + E);             // N*12 fp16
    float*  aggx   = (float*)(x16 + (size_t)N * IN_CH + 8);   // N*12 f32
    __half* h2     = (__half*)(aggx + (size_t)N * IN_CH);     // N*64 fp16

    const int nchunks = (E + CHUNK - 1) / CHUNK;

    k_zero_i<<<(NB + 255) / 256, 256, 0, stream>>>(bcnt, NB);
    k_cvt<<<(N * IN_CH + 255) / 256, 256, 0, stream>>>(x, x16, N * IN_CH);
    k_bhist<<<nchunks, 256, 0, stream>>>(col, bcnt, E, NB);
    k_bscan<<<1, 256, 0, stream>>>(bcnt, bstart, gcur, start + N, E, NB);
    k_bucket<<<nchunks, 256, 0, stream>>>(row, col, gcur, bbuf, E, NB);
    k_csr<<<NB, 256, 0, stream>>>(bstart, bbuf, start, dinv, rs, N);

    k_gather_x<<<(N + 15) / 16, 192, 0, stream>>>(start, dinv, rs, x16, aggx, N);
    k_mlp<<<(N + 63) / 64, 256, 0, stream>>>(aggx, W1, b1, W2, h2, N);
    k_gather2<<<(N + 3) / 4, 256, 0, stream>>>(start, dinv, rs, h2, b2, out, N);
}

// Round 12
// 192.507 us; speedup vs baseline: 1.7229x; 1.0104x over previous
//
#include <hip/hip_runtime.h>
#include <hip/hip_fp16.h>

// 2-layer GCN, CSR-gather formulation (no float atomics).
// A_norm·(x@W1) = (A_norm·x)@W1 -> layer-1 aggregation in 12-ch space.
// CSR built by two-level LDS bucket sort (run-coalesced writes; scattered
// single-pass fill measured sector-bound at 64B/edge in r4/r7/r8).
// bbuf packed: (row<<7)|local_col (row < 2^17). rs payload = row only.
// RACE LESSON (r11): gather source values (dinv/x of arbitrary nodes) must be
// produced by a PRIOR kernel — k_csr writes all dinv, THEN gathers launch.
// x and h2 in fp16 (measured safe r8-r10). MLP fused per 64-node tile.

#define IN_CH 12
#define HID 128
#define OUTC 64
#define PADK 132   // hidden-tile row stride in floats (breaks pow2 bank stride)
#define BSH 7      // bucket = 128 dest nodes
#define NBMAX 1024 // supports N <= 131072
#define CHUNK 4096 // edges per k_bucket block
#define SORTMAX 4096

__global__ void k_zero_i(int* __restrict__ p, int n) {
    int i = blockIdx.x * blockDim.x + threadIdx.x;
    if (i < n) p[i] = 0;
}

__global__ void k_cvt(const float* __restrict__ x, __half* __restrict__ x16, int n) {
    int i = blockIdx.x * blockDim.x + threadIdx.x;
    if (i < n) x16[i] = __float2half(x[i]);
}

// ---- CSR build pass 1: bucket histogram (LDS-privatized) ----
__global__ __launch_bounds__(256) void k_bhist(
    const int* __restrict__ col, int* __restrict__ bcnt, int E, int NB) {
    __shared__ int lh[NBMAX];
    int t = threadIdx.x;
    for (int i = t; i < NB; i += 256) lh[i] = 0;
    __syncthreads();
    int base = blockIdx.x * CHUNK;
    int end = min(base + CHUNK, E);
    for (int e = base + t; e < end; e += 256)
        atomicAdd(&lh[col[e] >> BSH], 1);
    __syncthreads();
    for (int i = t; i < NB; i += 256)
        if (lh[i]) atomicAdd(&bcnt[i], lh[i]);
}

// ---- pass 2: scan bucket counts -> bstart, gcur; also start[N]=E ----
__global__ __launch_bounds__(256) void k_bscan(
    const int* __restrict__ bcnt, int* __restrict__ bstart,
    int* __restrict__ gcur, int* __restrict__ startN, int E, int NB) {
    __shared__ int part[256];
    int t = threadIdx.x;
    int v[4]; int s = 0;
#pragma unroll
    for (int j = 0; j < 4; ++j) { int b = t * 4 + j; v[j] = (b < NB) ? bcnt[b] : 0; s += v[j]; }
    part[t] = s;
    __syncthreads();
    for (int off = 1; off < 256; off <<= 1) {
        int u = (t >= off) ? part[t - off] : 0;
        __syncthreads();
        part[t] += u;
        __syncthreads();
    }
    int base = (t > 0) ? part[t - 1] : 0;
#pragma unroll
    for (int j = 0; j < 4; ++j) {
        int b = t * 4 + j;
        if (b < NB) { bstart[b] = base; gcur[b] = base; }
        base += v[j];
    }
    if (t == 255) bstart[NB] = base;  // == E
    if (t == 0) *startN = E;          // start[N] = E
}

// ---- pass 3: LDS-staged bucket append; writes packed (row<<7)|lcol ----
__global__ __launch_bounds__(256) void k_bucket(
    const int* __restrict__ row, const int* __restrict__ col,
    int* __restrict__ gcur, int* __restrict__ bbuf, int E, int NB) {
    __shared__ int lh[NBMAX], lstart[NBMAX], lcur[NBMAX], gb[NBMAX];
    __shared__ int part[256];
    __shared__ int2 lbuf[CHUNK];  // 32 KiB
    int t = threadIdx.x;
    for (int i = t; i < NB; i += 256) lh[i] = 0;
    __syncthreads();
    int base0 = blockIdx.x * CHUNK;
    int end = min(base0 + CHUNK, E);
    for (int e = base0 + t; e < end; e += 256)
        atomicAdd(&lh[col[e] >> BSH], 1);
    __syncthreads();
    int v[4]; int s = 0;
#pragma unroll
    for (int j = 0; j < 4; ++j) { int b = t * 4 + j; v[j] = (b < NB) ? lh[b] : 0; s += v[j]; }
    part[t] = s;
    __syncthreads();
    for (int off = 1; off < 256; off <<= 1) {
        int u = (t >= off) ? part[t - off] : 0;
        __syncthreads();
        part[t] += u;
        __syncthreads();
    }
    int pb = (t > 0) ? part[t - 1] : 0;
#pragma unroll
    for (int j = 0; j < 4; ++j) {
        int b = t * 4 + j;
        if (b < NB) lstart[b] = pb;
        pb += v[j];
    }
    __syncthreads();
    for (int i = t; i < NB; i += 256) {
        int c = lh[i];
        gb[i] = c ? atomicAdd(&gcur[i], c) : 0;
        lcur[i] = lstart[i];
    }
    __syncthreads();
    for (int e = base0 + t; e < end; e += 256) {
        int c = col[e];
        int p = atomicAdd(&lcur[c >> BSH], 1);
        lbuf[p] = make_int2(row[e], c);
    }
    __syncthreads();
    int cN = end - base0;
    for (int i = t; i < cN; i += 256) {
        int2 rc = lbuf[i];
        int b = rc.y >> BSH;
        bbuf[gb[b] + (i - lstart[b])] = (rc.x << BSH) | (rc.y & 127);
    }
}

// ---- pass 4: per-bucket CSR: start/dinv + LDS sort -> coalesced rs write ----
__global__ __launch_bounds__(256) void k_csr(
    const int* __restrict__ bstart, const int* __restrict__ bbuf,
    int* __restrict__ start, float* __restrict__ dinv,
    int* __restrict__ rs, int N) {
    int me = blockIdx.x;
    int lo = me << BSH;
    int bs = bstart[me], be = bstart[me + 1];
    int cntb = be - bs;
    __shared__ int lh[128], lsc[128];
    __shared__ int lsort[SORTMAX];  // 16 KiB
    int t = threadIdx.x;
    bool lds_ok = (cntb <= SORTMAX);
    if (t < 128) lh[t] = 0;
    __syncthreads();
    for (int i = t; i < cntb; i += 256)
        atomicAdd(&lh[bbuf[bs + i] & 127], 1);
    __syncthreads();
    if (t < 128) lsc[t] = lh[t];
    __syncthreads();
    for (int off = 1; off < 128; off <<= 1) {
        int u = (t < 128 && t >= off) ? lsc[t - off] : 0;
        __syncthreads();
        if (t < 128) lsc[t] += u;
        __syncthreads();
    }
    if (t < 128) {
        int excl = lsc[t] - lh[t];
        int n = lo + t;
        if (n < N) {
            start[n] = bs + excl;
            dinv[n] = rsqrtf((float)lh[t] + 1.0f);
        }
        lsc[t] = excl;  // reuse as cursor
    }
    __syncthreads();
    for (int i = t; i < cntb; i += 256) {
        int v = bbuf[bs + i];
        int p = atomicAdd(&lsc[v & 127], 1);
        int r = v >> BSH;
        if (lds_ok) lsort[p] = r; else rs[bs + p] = r;
    }
    __syncthreads();
    if (lds_ok)  // coalesced rs write-out
        for (int i = t; i < cntb; i += 256) rs[bs + i] = lsort[i];
}

// ---- layer 1 gather: aggx = A_norm·x (12 ch, fp16 x, 8-deep pipeline) ----
__global__ __launch_bounds__(192) void k_gather_x(
    const int* __restrict__ start, const float* __restrict__ dinv,
    const int* __restrict__ rs, const __half* __restrict__ x16,
    float* __restrict__ aggx, int N) {
    int ln = threadIdx.x / 12;
    int c  = threadIdx.x % 12;
    int n  = blockIdx.x * 16 + ln;
    if (n >= N) return;
    float dv = dinv[n];
    int s0 = start[n], k = start[n + 1] - s0;
    float acc = __half2float(x16[(size_t)n * IN_CH + c]) * dv * dv;
    int j = 0;
    for (; j + 8 <= k; j += 8) {
        int r[8];
#pragma unroll
        for (int q = 0; q < 8; ++q) r[q] = rs[s0 + j + q];
        float nm[8], vv[8];
#pragma unroll
        for (int q = 0; q < 8; ++q) nm[q] = dinv[r[q]] * dv;
#pragma unroll
        for (int q = 0; q < 8; ++q) vv[q] = __half2float(x16[(size_t)r[q] * IN_CH + c]);
#pragma unroll
        for (int q = 0; q < 8; ++q) acc = fmaf(vv[q], nm[q], acc);
    }
    for (; j + 4 <= k; j += 4) {
        int r0 = rs[s0 + j], r1 = rs[s0 + j + 1], r2 = rs[s0 + j + 2], r3 = rs[s0 + j + 3];
        float n0 = dinv[r0] * dv, n1 = dinv[r1] * dv, n2 = dinv[r2] * dv, n3 = dinv[r3] * dv;
        float v0 = __half2float(x16[(size_t)r0 * IN_CH + c]);
        float v1 = __half2float(x16[(size_t)r1 * IN_CH + c]);
        float v2 = __half2float(x16[(size_t)r2 * IN_CH + c]);
        float v3 = __half2float(x16[(size_t)r3 * IN_CH + c]);
        acc = fmaf(v0, n0, acc); acc = fmaf(v1, n1, acc);
        acc = fmaf(v2, n2, acc); acc = fmaf(v3, n3, acc);
    }
    for (; j < k; ++j) {
        int r = rs[s0 + j];
        acc = fmaf(__half2float(x16[(size_t)r * IN_CH + c]), dinv[r] * dv, acc);
    }
    aggx[(size_t)n * IN_CH + c] = acc;
}

// ---- fused MLP: h2 = fp16( relu(aggx@W1 + b1) @ W2 ), per 64-node tile ----
__global__ __launch_bounds__(256) void k_mlp(
    const float* __restrict__ aggx, const float* __restrict__ W1,
    const float* __restrict__ b1, const float* __restrict__ W2,
    __half* __restrict__ h2, int N) {
    __shared__ float w1s[IN_CH * HID];   // 6 KiB
    __shared__ float ws[HID * OUTC];     // 32 KiB
    __shared__ float axs[64 * IN_CH];    // 3 KiB
    __shared__ float hs[64 * PADK];      // 33.8 KiB
    int t = threadIdx.x;
    for (int i = t; i < (HID * OUTC) / 4; i += 256)
        ((float4*)ws)[i] = ((const float4*)W2)[i];
    for (int i = t; i < IN_CH * HID; i += 256) w1s[i] = W1[i];
    long long base = (long long)blockIdx.x * 64;
    for (int i = t; i < 64 * IN_CH; i += 256) {
        long long n = base + i / IN_CH;
        axs[i] = (n < N) ? aggx[base * IN_CH + i] : 0.0f;
    }
    __syncthreads();
    {
        int k    = t & 127;
        int half = t >> 7;
        float w[IN_CH];
#pragma unroll
        for (int j = 0; j < IN_CH; ++j) w[j] = w1s[j * HID + k];
        float bb = b1[k];
        for (int r = 0; r < 32; ++r) {
            int row = half * 32 + r;
            float acc = bb;
#pragma unroll
            for (int j = 0; j < IN_CH; ++j)
                acc = fmaf(axs[row * IN_CH + j], w[j], acc);
            hs[row * PADK + k] = fmaxf(acc, 0.0f);
        }
    }
    __syncthreads();
    int tc = t & 15;
    int tr = t >> 4;
    float acc[4][4] = {};
    const float* ar = hs + 4 * tr * PADK;
#pragma unroll 8
    for (int k = 0; k < HID; k += 4) {
        float4 a[4], w[4];
#pragma unroll
        for (int j = 0; j < 4; ++j) a[j] = *(const float4*)(ar + j * PADK + k);
#pragma unroll
        for (int kk = 0; kk < 4; ++kk) w[kk] = *(const float4*)(ws + (k + kk) * OUTC + 4 * tc);
#pragma unroll
        for (int kk = 0; kk < 4; ++kk) {
            float aw[4] = {w[kk].x, w[kk].y, w[kk].z, w[kk].w};
#pragma unroll
            for (int j = 0; j < 4; ++j) {
                float av = (kk == 0) ? a[j].x : (kk == 1) ? a[j].y : (kk == 2) ? a[j].z : a[j].w;
                acc[j][0] = fmaf(av, aw[0], acc[j][0]);
                acc[j][1] = fmaf(av, aw[1], acc[j][1]);
                acc[j][2] = fmaf(av, aw[2], acc[j][2]);
                acc[j][3] = fmaf(av, aw[3], acc[j][3]);
            }
        }
    }
#pragma unroll
    for (int j = 0; j < 4; ++j) {
        long long r = base + 4 * tr + j;
        if (r < N) {
            __half2* d = (__half2*)(h2 + r * OUTC + 4 * tc);
            d[0] = __floats2half2_rn(acc[j][0], acc[j][1]);
            d[1] = __floats2half2_rn(acc[j][2], acc[j][3]);
        }
    }
}

// ---- layer 2 gather: out = A_norm·h2 + b2 (64 ch, fp16 h2, 16-deep pipe) ----
__global__ __launch_bounds__(256) void k_gather2(
    const int* __restrict__ start, const float* __restrict__ dinv,
    const int* __restrict__ rs, const __half* __restrict__ h2,
    const float* __restrict__ b2, float* __restrict__ out, int N) {
    int ln = threadIdx.x >> 6;
    int c  = threadIdx.x & 63;
    int n  = blockIdx.x * 4 + ln;
    if (n >= N) return;
    float dv = dinv[n];
    int s0 = start[n], k = start[n + 1] - s0;
    float acc = fmaf(__half2float(h2[(size_t)n * OUTC + c]), dv * dv, b2[c]);
    int j = 0;
    for (; j + 16 <= k; j += 16) {
        int r[16];
#pragma unroll
        for (int q = 0; q < 16; ++q) r[q] = rs[s0 + j + q];
        float nm[16];
#pragma unroll
        for (int q = 0; q < 16; ++q) nm[q] = dinv[r[q]] * dv;
        float vv[16];
#pragma unroll
        for (int q = 0; q < 16; ++q) vv[q] = __half2float(h2[(size_t)r[q] * OUTC + c]);
#pragma unroll
        for (int q = 0; q < 16; ++q) acc = fmaf(vv[q], nm[q], acc);
    }
    for (; j + 8 <= k; j += 8) {
        int r[8];
#pragma unroll
        for (int q = 0; q < 8; ++q) r[q] = rs[s0 + j + q];
        float nm[8], vv[8];
#pragma unroll
        for (int q = 0; q < 8; ++q) nm[q] = dinv[r[q]] * dv;
#pragma unroll
        for (int q = 0; q < 8; ++q) vv[q] = __half2float(h2[(size_t)r[q] * OUTC + c]);
#pragma unroll
        for (int q = 0; q < 8; ++q) acc = fmaf(vv[q], nm[q], acc);
    }
    for (; j + 4 <= k; j += 4) {
        int r0 = rs[s0 + j], r1 = rs[s0 + j + 1], r2 = rs[s0 + j + 2], r3 = rs[s0 + j + 3];
        float n0 = dinv[r0] * dv, n1 = dinv[r1] * dv, n2 = dinv[r2] * dv, n3 = dinv[r3] * dv;
        float v0 = __half2float(h2[(size_t)r0 * OUTC + c]);
        float v1 = __half2float(h2[(size_t)r1 * OUTC + c]);
        float v2 = __half2float(h2[(size_t)r2 * OUTC + c]);
        float v3 = __half2float(h2[(size_t)r3 * OUTC + c]);
        acc = fmaf(v0, n0, acc); acc = fmaf(v1, n1, acc);
        acc = fmaf(v2, n2, acc); acc = fmaf(v3, n3, acc);
    }
    for (; j < k; ++j) {
        int r = rs[s0 + j];
        acc = fmaf(__half2float(h2[(size_t)r * OUTC + c]), dinv[r] * dv, acc);
    }
    out[(size_t)n * OUTC + c] = acc;
}

extern "C" void kernel_launch(void* const* d_in, const int* in_sizes, int n_in,
                              void* d_out, int out_size, void* d_ws, size_t ws_size,
                              hipStream_t stream) {
    const float* x  = (const float*)d_in[0];
    const int*   ei = (const int*)d_in[1];
    const float* W1 = (const float*)d_in[2];
    const float* b1 = (const float*)d_in[3];
    const float* W2 = (const float*)d_in[4];
    const float* b2 = (const float*)d_in[5];
    float* out = (float*)d_out;

    const int N = in_sizes[0] / IN_CH;
    const int E = in_sizes[1] / 2;
    const int* row = ei;
    const int* col = ei + E;
    const int NB = (N + 127) >> BSH;  // 782 for N=100000 (<= NBMAX)

    char* ws = (char*)d_ws;
    int*    bcnt   = (int*)ws;                      // NB (zeroed)
    int*    bstart = bcnt + NBMAX;                  // NB+1
    int*    gcur   = bstart + NBMAX + 8;            // NB
    int*    start  = gcur + NBMAX;                  // N+1
    float*  dinv   = (float*)(start + N + 8);       // N
    char*   p      = (char*)(dinv + N);
    p = (char*)(((uintptr_t)p + 255) & ~(uintptr_t)255);
    int*    bbuf   = (int*)p;                       // E packed ints (6.4 MB)
    int*    rs     = bbuf + E;                      // E ints (6.4 MB)
    __half* x16    = (__half*)(rs + E);             // N*12 fp16
    float*  aggx   = (float*)(x16 + (size_t)N * IN_CH + 8);   // N*12 f32
    __half* h2     = (__half*)(aggx + (size_t)N * IN_CH);     // N*64 fp16

    const int nchunks = (E + CHUNK - 1) / CHUNK;

    k_zero_i<<<(NB + 255) / 256, 256, 0, stream>>>(bcnt, NB);
    k_cvt<<<(N * IN_CH + 255) / 256, 256, 0, stream>>>(x, x16, N * IN_CH);
    k_bhist<<<nchunks, 256, 0, stream>>>(col, bcnt, E, NB);
    k_bscan<<<1, 256, 0, stream>>>(bcnt, bstart, gcur, start + N, E, NB);
    k_bucket<<<nchunks, 256, 0, stream>>>(row, col, gcur, bbuf, E, NB);
    k_csr<<<NB, 256, 0, stream>>>(bstart, bbuf, start, dinv, rs, N);

    k_gather_x<<<(N + 15) / 16, 192, 0, stream>>>(start, dinv, rs, x16, aggx, N);
    k_mlp<<<(N + 63) / 64, 256, 0, stream>>>(aggx, W1, b1, W2, h2, N);
    k_gather2<<<(N + 3) / 4, 256, 0, stream>>>(start, dinv, rs, h2, b2, out, N);
}